// Round 8
// baseline (231.032 us; speedup 1.0000x reference)
//
#include <hip/hip_runtime.h>

#define KL   19
#define K2   361
#define W    256
#define H    256
#define HW   65536
#define C    3
#define PADL 9
#define B    2
#define TC   34            // tile cols: 16 pixels + 18 halo
#define TR   20            // tile rows: 2 pixel rows + 18 halo
#define TPOS (TR * TC)     // 680 spatial positions

// Sum across each 16-lane DPP row via v_add_f32 row_shr:{1,2,4,8}.
// Lane 15 of each row holds the full 16-lane sum.
__device__ __forceinline__ float dpp_sum16(float x) {
    int t;
    t = __builtin_amdgcn_update_dpp(0, __float_as_int(x), 0x111, 0xF, 0xF, true); // row_shr:1
    x += __int_as_float(t);
    t = __builtin_amdgcn_update_dpp(0, __float_as_int(x), 0x112, 0xF, 0xF, true); // row_shr:2
    x += __int_as_float(t);
    t = __builtin_amdgcn_update_dpp(0, __float_as_int(x), 0x114, 0xF, 0xF, true); // row_shr:4
    x += __int_as_float(t);
    t = __builtin_amdgcn_update_dpp(0, __float_as_int(x), 0x118, 0xF, 0xF, true); // row_shr:8
    x += __int_as_float(t);
    return x;
}

// R6 geometry (best: 35.1us): one block = 16 cols x 2 rows = 32 px, 4096
// blocks, (256,8) = 32 waves/CU. New in R8: weight loads are STAGGERED in
// half-bursts between compute chunks (B0 -> comp0a -> B1a -> comp0b -> B1b
// -> comp1a -> comp1b) so the memory pipe always has outstanding requests
// while bounding live weight-regs to 23+12=35 (no spill at the 64-reg cap).
// R7's lesson: a monolithic 46-load hoist + lower occupancy regresses.
__global__ __launch_bounds__(256, 8) void blur_fused(
    const float* __restrict__ in,     // (B, C, 256, 256)
    const float* __restrict__ kern,   // (B, HW, 19, 19)
    float* __restrict__ out)          // (B, C, 256, 256)
{
    __shared__ float tile[TPOS * 4];  // 10880 B

    const int tid = threadIdx.x;
    const int bid = blockIdx.x;
    const int b   = bid >> 11;             // 2048 blocks per batch
    const int rem = bid & 2047;
    const int i0  = (rem >> 4) << 1;       // row-pair base (0,2,...,254)
    const int j0  = (rem & 15) << 4;       // col base (multiple of 16)

    // ---- stage 20x34x3 window, plane-major (coalesced 256B per inst) ----
    const float* in_b = in + (size_t)b * (C * HW);
    #pragma unroll
    for (int k = 0; k < 8; ++k) {
        const int s = tid + 256 * k;       // 0..2047
        if (s < TPOS * 3) {                // 2040 useful slots
            const int ch  = s / TPOS;      // plane index 0..2 (magic-mul)
            const int pos = s - ch * TPOS;
            const int rr  = pos / TC;
            const int cc  = pos - rr * TC;
            int ro = i0 + rr - PADL;                   // [-9, 264]
            ro = (ro < 0) ? -ro : ro;
            ro = (ro > H - 1) ? 2 * (H - 1) - ro : ro;
            int co = j0 + cc - PADL;
            co = (co < 0) ? -co : co;
            co = (co > W - 1) ? 2 * (W - 1) - co : co;
            tile[4 * pos + ch] = in_b[ch * HW + ro * W + co];
        }
    }
    __syncthreads();

    const int sub = tid & 15;              // lane within pixel group
    const int q   = tid >> 4;              // pixel column within block
    const float scale = 1.0f / (float)K2;

    const int ij0 = (i0 << 8) + j0 + q;                  // row-0 pixel
    const float* krow0 = kern + ((size_t)b * HW + ij0) * K2 + sub;
    const float* krow1 = krow0 + (size_t)W * K2;         // row-1 pixel

    float a00 = 0.f, a01 = 0.f, a02 = 0.f;   // row 0 accumulators
    float a10 = 0.f, a11 = 0.f, a12 = 0.f;   // row 1 accumulators

    // ---- B0: row 0 full burst (23 loads) ----
    float w0[23];
    #pragma unroll
    for (int c = 0; c < 23; ++c) {
        const int t = sub + 16 * c;
        w0[c] = (t < K2) ? krow0[16 * c] : 0.f;          // guard only c==22
    }

    // ---- compute0a: taps 0..11 of row 0 (consumes w0[0..11]) ----
    #pragma unroll
    for (int c = 0; c < 12; ++c) {
        const int t  = sub + 16 * c;
        const int ki = t / KL;
        const int kj = t - ki * KL;
        const float* src = &tile[(ki * TC + kj + q) * 4];
        a00 += w0[c] * src[0];
        a01 += w0[c] * src[1];
        a02 += w0[c] * src[2];
    }

    // ---- B1a: row 1 first half-burst (12 loads, reuses freed regs) ----
    float w1a[12];
    #pragma unroll
    for (int c = 0; c < 12; ++c) {
        w1a[c] = krow1[16 * c];
    }

    // ---- compute0b: taps 12..22 of row 0 ----
    #pragma unroll
    for (int c = 12; c < 23; ++c) {
        int t = sub + 16 * c;
        if (t > K2 - 1) t = K2 - 1;                      // clamp (w==0 there)
        const int ki = t / KL;
        const int kj = t - ki * KL;
        const float* src = &tile[(ki * TC + kj + q) * 4];
        a00 += w0[c] * src[0];
        a01 += w0[c] * src[1];
        a02 += w0[c] * src[2];
    }

    // ---- B1b: row 1 second half-burst (11 loads) ----
    float w1b[11];
    #pragma unroll
    for (int c = 12; c < 23; ++c) {
        const int t = sub + 16 * c;
        w1b[c - 12] = (t < K2) ? krow1[16 * c] : 0.f;
    }

    // row 0 done: reduce + store
    a00 = dpp_sum16(a00);
    a01 = dpp_sum16(a01);
    a02 = dpp_sum16(a02);
    if (sub == 15) {
        float* ob = out + (size_t)b * (C * HW) + ij0;
        ob[0]      = a00 * scale;
        ob[HW]     = a01 * scale;
        ob[2 * HW] = a02 * scale;
    }

    // ---- compute1a: taps 0..11 of row 1 (tile shifted one row: +TC) ----
    #pragma unroll
    for (int c = 0; c < 12; ++c) {
        const int t  = sub + 16 * c;
        const int ki = t / KL;
        const int kj = t - ki * KL;
        const float* src = &tile[((ki + 1) * TC + kj + q) * 4];
        a10 += w1a[c] * src[0];
        a11 += w1a[c] * src[1];
        a12 += w1a[c] * src[2];
    }

    // ---- compute1b: taps 12..22 of row 1 ----
    #pragma unroll
    for (int c = 12; c < 23; ++c) {
        int t = sub + 16 * c;
        if (t > K2 - 1) t = K2 - 1;
        const int ki = t / KL;
        const int kj = t - ki * KL;
        const float* src = &tile[((ki + 1) * TC + kj + q) * 4];
        a10 += w1b[c - 12] * src[0];
        a11 += w1b[c - 12] * src[1];
        a12 += w1b[c - 12] * src[2];
    }

    a10 = dpp_sum16(a10);
    a11 = dpp_sum16(a11);
    a12 = dpp_sum16(a12);
    if (sub == 15) {
        float* ob = out + (size_t)b * (C * HW) + ij0 + W;
        ob[0]      = a10 * scale;
        ob[HW]     = a11 * scale;
        ob[2 * HW] = a12 * scale;
    }
}

extern "C" void kernel_launch(void* const* d_in, const int* in_sizes, int n_in,
                              void* d_out, int out_size, void* d_ws, size_t ws_size,
                              hipStream_t stream) {
    const float* in   = (const float*)d_in[0];
    const float* kern = (const float*)d_in[1];
    float* out        = (float*)d_out;

    dim3 grid(B * (H / 2) * (W / 16)), block(256);   // 4096 blocks, 32 px each
    hipLaunchKernelGGL(blur_fused, grid, block, 0, stream, in, kern, out);
}

// Round 9
// 41.613 us; speedup vs baseline: 5.5520x; 5.5520x over previous
//
#include <hip/hip_runtime.h>

#define KL   19
#define K2   361
#define W    256
#define H    256
#define HW   65536
#define C    3
#define PADL 9
#define B    2
#define TC   34            // tile cols: 16 pixels + 18 halo
#define TR   20            // tile rows: 2 pixel rows + 18 halo
#define TPOS (TR * TC)     // 680 spatial positions

// Sum across each 16-lane DPP row via v_add_f32 row_shr:{1,2,4,8}.
// Lane 15 of each row holds the full 16-lane sum.
__device__ __forceinline__ float dpp_sum16(float x) {
    int t;
    t = __builtin_amdgcn_update_dpp(0, __float_as_int(x), 0x111, 0xF, 0xF, true); // row_shr:1
    x += __int_as_float(t);
    t = __builtin_amdgcn_update_dpp(0, __float_as_int(x), 0x112, 0xF, 0xF, true); // row_shr:2
    x += __int_as_float(t);
    t = __builtin_amdgcn_update_dpp(0, __float_as_int(x), 0x114, 0xF, 0xF, true); // row_shr:4
    x += __int_as_float(t);
    t = __builtin_amdgcn_update_dpp(0, __float_as_int(x), 0x118, 0xF, 0xF, true); // row_shr:8
    x += __int_as_float(t);
    return x;
}

// R6 structure (proven 35.1us): one block = 16 cols x 2 rows = 32 px, 4096
// blocks, (256,8) = 32 waves/CU, sequential per-row {burst 23 -> compute ->
// DPP -> store}. Single change vs R6: an 8-load prefetch of row-1 weights
// before row-0's compute keeps memory requests outstanding through the
// compute phase. Liveness discipline (R7/R8 lessons): peak live weight regs
// = 23 + 8 (not 23+23 [R7: occupancy loss] nor 23+12+dual-accums [R8:
// wholesale scratch spill, 460 MB of traffic]); row-1 accumulators are
// born only after row-0 retires.
__global__ __launch_bounds__(256, 8) void blur_fused(
    const float* __restrict__ in,     // (B, C, 256, 256)
    const float* __restrict__ kern,   // (B, HW, 19, 19)
    float* __restrict__ out)          // (B, C, 256, 256)
{
    __shared__ float tile[TPOS * 4];  // 10880 B

    const int tid = threadIdx.x;
    const int bid = blockIdx.x;
    const int b   = bid >> 11;             // 2048 blocks per batch
    const int rem = bid & 2047;
    const int i0  = (rem >> 4) << 1;       // row-pair base (0,2,...,254)
    const int j0  = (rem & 15) << 4;       // col base (multiple of 16)

    // ---- stage 20x34x3 window, plane-major (coalesced 256B per inst) ----
    const float* in_b = in + (size_t)b * (C * HW);
    #pragma unroll
    for (int k = 0; k < 8; ++k) {
        const int s = tid + 256 * k;       // 0..2047
        if (s < TPOS * 3) {                // 2040 useful slots
            const int ch  = s / TPOS;      // plane index 0..2 (magic-mul)
            const int pos = s - ch * TPOS;
            const int rr  = pos / TC;
            const int cc  = pos - rr * TC;
            int ro = i0 + rr - PADL;                   // [-9, 264]
            ro = (ro < 0) ? -ro : ro;
            ro = (ro > H - 1) ? 2 * (H - 1) - ro : ro;
            int co = j0 + cc - PADL;
            co = (co < 0) ? -co : co;
            co = (co > W - 1) ? 2 * (W - 1) - co : co;
            tile[4 * pos + ch] = in_b[ch * HW + ro * W + co];
        }
    }
    __syncthreads();

    const int sub = tid & 15;              // lane within pixel group
    const int q   = tid >> 4;              // pixel column within block
    const float scale = 1.0f / (float)K2;

    const int ij0 = (i0 << 8) + j0 + q;                  // row-0 pixel
    const float* krow0 = kern + ((size_t)b * HW + ij0) * K2 + sub;
    const float* krow1 = krow0 + (size_t)W * K2;         // row-1 pixel

    // ---- row-0 burst: 23 coalesced dword loads ----
    float w0[23];
    #pragma unroll
    for (int c = 0; c < 23; ++c) {
        const int t = sub + 16 * c;
        w0[c] = (t < K2) ? krow0[16 * c] : 0.f;          // guard only c==22
    }

    // ---- row-1 prefetch: 8 loads (t = sub+16c <= 127 < 361, no guard) ----
    float w1[23];
    #pragma unroll
    for (int c = 0; c < 8; ++c) {
        w1[c] = krow1[16 * c];
    }

    // ---- row-0 compute ----
    {
        float a0 = 0.f, a1 = 0.f, a2 = 0.f;
        #pragma unroll
        for (int c = 0; c < 23; ++c) {
            int t = sub + 16 * c;
            if (t > K2 - 1) t = K2 - 1;                  // clamp (w==0 there)
            const int ki = t / KL;
            const int kj = t - ki * KL;
            const float* src = &tile[(ki * TC + kj + q) * 4];
            a0 += w0[c] * src[0];
            a1 += w0[c] * src[1];
            a2 += w0[c] * src[2];
        }
        a0 = dpp_sum16(a0);
        a1 = dpp_sum16(a1);
        a2 = dpp_sum16(a2);
        if (sub == 15) {
            float* ob = out + (size_t)b * (C * HW) + ij0;
            ob[0]      = a0 * scale;
            ob[HW]     = a1 * scale;
            ob[2 * HW] = a2 * scale;
        }
    }

    // ---- row-1 remaining burst: 15 loads ----
    #pragma unroll
    for (int c = 8; c < 23; ++c) {
        const int t = sub + 16 * c;
        w1[c] = (t < K2) ? krow1[16 * c] : 0.f;          // guard only c==22
    }

    // ---- row-1 compute (tile shifted one row: +TC positions) ----
    {
        float a0 = 0.f, a1 = 0.f, a2 = 0.f;
        #pragma unroll
        for (int c = 0; c < 23; ++c) {
            int t = sub + 16 * c;
            if (t > K2 - 1) t = K2 - 1;
            const int ki = t / KL;
            const int kj = t - ki * KL;
            const float* src = &tile[((ki + 1) * TC + kj + q) * 4];
            a0 += w1[c] * src[0];
            a1 += w1[c] * src[1];
            a2 += w1[c] * src[2];
        }
        a0 = dpp_sum16(a0);
        a1 = dpp_sum16(a1);
        a2 = dpp_sum16(a2);
        if (sub == 15) {
            float* ob = out + (size_t)b * (C * HW) + ij0 + W;
            ob[0]      = a0 * scale;
            ob[HW]     = a1 * scale;
            ob[2 * HW] = a2 * scale;
        }
    }
}

extern "C" void kernel_launch(void* const* d_in, const int* in_sizes, int n_in,
                              void* d_out, int out_size, void* d_ws, size_t ws_size,
                              hipStream_t stream) {
    const float* in   = (const float*)d_in[0];
    const float* kern = (const float*)d_in[1];
    float* out        = (float*)d_out;

    dim3 grid(B * (H / 2) * (W / 16)), block(256);   // 4096 blocks, 32 px each
    hipLaunchKernelGGL(blur_fused, grid, block, 0, stream, in, kern, out);
}

// Round 10
// 35.519 us; speedup vs baseline: 6.5045x; 1.1716x over previous
//
#include <hip/hip_runtime.h>

#define KL   19
#define K2   361
#define W    256
#define H    256
#define HW   65536
#define C    3
#define PADL 9
#define B    2
#define TC   34            // tile cols: 16 pixels + 18 halo
#define TR   20            // tile rows: 2 pixel rows + 18 halo
#define TPOS (TR * TC)     // 680 spatial positions

// Sum across each 16-lane DPP row via v_add_f32 row_shr:{1,2,4,8}.
// Lane 15 of each row holds the full 16-lane sum.
__device__ __forceinline__ float dpp_sum16(float x) {
    int t;
    t = __builtin_amdgcn_update_dpp(0, __float_as_int(x), 0x111, 0xF, 0xF, true); // row_shr:1
    x += __int_as_float(t);
    t = __builtin_amdgcn_update_dpp(0, __float_as_int(x), 0x112, 0xF, 0xF, true); // row_shr:2
    x += __int_as_float(t);
    t = __builtin_amdgcn_update_dpp(0, __float_as_int(x), 0x114, 0xF, 0xF, true); // row_shr:4
    x += __int_as_float(t);
    t = __builtin_amdgcn_update_dpp(0, __float_as_int(x), 0x118, 0xF, 0xF, true); // row_shr:8
    x += __int_as_float(t);
    return x;
}

// R6 structure — the measured optimum (35.1 us, 5.5 TB/s effective kernel-
// tensor stream = 88% of the 6.29 TB/s demonstrated read ceiling).
// One block = 16 cols x 2 rows = 32 output pixels (4096 blocks, (256,8) =
// 32 waves/CU). The shared 20x34x3 window is staged once (plane-major
// global reads, channel-interleaved [pos][4] in LDS => each tap is one
// 16B-aligned ds_read_b96) and reused by two sequential row passes. 16
// lanes per pixel stream that pixel's 19x19 kernel (coalesced dwords, one
// base + imm offsets, 23-deep burst). DPP (VALU) reduction, no DS shuffles.
// R7/R8/R9 all showed: any structure with >1 live weight burst per wave
// regresses (occupancy loss, scratch spill, or live-range extension) —
// TLP, not per-wave ILP, hides the compute-phase memory gap.
__global__ __launch_bounds__(256, 8) void blur_fused(
    const float* __restrict__ in,     // (B, C, 256, 256)
    const float* __restrict__ kern,   // (B, HW, 19, 19)
    float* __restrict__ out)          // (B, C, 256, 256)
{
    __shared__ float tile[TPOS * 4];  // 10880 B

    const int tid = threadIdx.x;
    const int bid = blockIdx.x;
    const int b   = bid >> 11;             // 2048 blocks per batch
    const int rem = bid & 2047;
    const int i0  = (rem >> 4) << 1;       // row-pair base (0,2,...,254)
    const int j0  = (rem & 15) << 4;       // col base (multiple of 16)

    // ---- stage 20x34x3 window, plane-major (coalesced 256B per inst) ----
    const float* in_b = in + (size_t)b * (C * HW);
    #pragma unroll
    for (int k = 0; k < 8; ++k) {
        const int s = tid + 256 * k;       // 0..2047
        if (s < TPOS * 3) {                // 2040 useful slots
            const int ch  = s / TPOS;      // plane index 0..2 (magic-mul)
            const int pos = s - ch * TPOS;
            const int rr  = pos / TC;
            const int cc  = pos - rr * TC;
            int ro = i0 + rr - PADL;                   // [-9, 264]
            ro = (ro < 0) ? -ro : ro;
            ro = (ro > H - 1) ? 2 * (H - 1) - ro : ro;
            int co = j0 + cc - PADL;
            co = (co < 0) ? -co : co;
            co = (co > W - 1) ? 2 * (W - 1) - co : co;
            tile[4 * pos + ch] = in_b[ch * HW + ro * W + co];
        }
    }
    __syncthreads();

    const int sub = tid & 15;              // lane within pixel group
    const int q   = tid >> 4;              // pixel column within block
    const float scale = 1.0f / (float)K2;

    #pragma unroll
    for (int r = 0; r < 2; ++r) {          // two pixel rows share the tile
        const int ij = ((i0 + r) << 8) + j0 + q;
        const float* krow = kern + ((size_t)b * HW + ij) * K2 + sub;

        // preload all 23 weights (coalesced: 4 full cache lines / wave-inst)
        float w[23];
        #pragma unroll
        for (int c = 0; c < 23; ++c) {
            const int t = sub + 16 * c;
            w[c] = (t < K2) ? krow[16 * c] : 0.f;      // guard only c==22
        }

        float a0 = 0.f, a1 = 0.f, a2 = 0.f;
        #pragma unroll
        for (int c = 0; c < 23; ++c) {
            int t = sub + 16 * c;
            if (t > K2 - 1) t = K2 - 1;                // clamp (w==0 there)
            const int ki = t / KL;
            const int kj = t - ki * KL;
            // r*TC folds into the ds_read immediate offset (544*r bytes)
            const float* src = &tile[((ki + r) * TC + kj + q) * 4];
            a0 += w[c] * src[0];
            a1 += w[c] * src[1];
            a2 += w[c] * src[2];
        }

        a0 = dpp_sum16(a0);
        a1 = dpp_sum16(a1);
        a2 = dpp_sum16(a2);

        if (sub == 15) {
            float* ob = out + (size_t)b * (C * HW) + ij;
            ob[0]      = a0 * scale;
            ob[HW]     = a1 * scale;
            ob[2 * HW] = a2 * scale;
        }
    }
}

extern "C" void kernel_launch(void* const* d_in, const int* in_sizes, int n_in,
                              void* d_out, int out_size, void* d_ws, size_t ws_size,
                              hipStream_t stream) {
    const float* in   = (const float*)d_in[0];
    const float* kern = (const float*)d_in[1];
    float* out        = (float*)d_out;

    dim3 grid(B * (H / 2) * (W / 16)), block(256);   // 4096 blocks, 32 px each
    hipLaunchKernelGGL(blur_fused, grid, block, 0, stream, in, kern, out);
}